// Round 18
// baseline (514.393 us; speedup 1.0000x reference)
//
#include <hip/hip_runtime.h>
#include <math.h>

#define NE 8192   // num_users == num_items
#define HT 1024   // histogram/scatter block threads
#define NCH 8     // slice chunks for two-level colscan/reduce
#define RT 512    // k_rows threads (8 waves)
#define NROWS 16  // rows per k_rows block = bucket size
#define NBK 512   // buckets per direction (NE / NROWS)
#define KMAX 10   // max bucket entries per thread (cap 5120 ~ 19 sigma above mean 3906)

// db3 analysis filters, reversed (cross-correlation of reversed filter == convolution)
__device__ __constant__ float LO_R[6] = {
    0.3326705529509569f, 0.8068915093133388f, 0.4598775021193313f,
    -0.13501102001039084f, -0.08544127388224149f, 0.035226291882100656f};
__device__ __constant__ float HI_RV[6] = {
    0.035226291882100656f, 0.08544127388224149f, -0.13501102001039084f,
    -0.4598775021193313f, 0.8068915093133388f, -0.3326705529509569f};

// 256-thread block reduce; valid on thread 0.
__device__ __forceinline__ float blockReduceSum(float v, float* red) {
    #pragma unroll
    for (int off = 32; off > 0; off >>= 1) v += __shfl_down(v, off);
    int lane = threadIdx.x & 63, wid = threadIdx.x >> 6;
    if (lane == 0) red[wid] = v;
    __syncthreads();
    float r = 0.f;
    if (threadIdx.x == 0) {
        int nw = blockDim.x >> 6;
        for (int i = 0; i < nw; ++i) r += red[i];
    }
    return r;
}

// ---------- setup: per-position impulse responses of the 3-level clipped DWT ----
__global__ void k_tables(float* __restrict__ resp, float4* __restrict__ Tdiag) {
    int a = blockIdx.x * blockDim.x + threadIdx.x;
    if (a >= NE) return;
    float lo1r[8], hi1r[8];
    int k1a = max(0, (a >> 1) - 3);
    #pragma unroll
    for (int t = 0; t < 8; ++t) {
        int k = k1a + t;
        int j = a - 2 * k + 4;
        bool ok = (j >= 0 && j <= 5 && k <= 4097);
        lo1r[t] = ok ? LO_R[j] : 0.f;
        hi1r[t] = ok ? HI_RV[j] : 0.f;
    }
    float lo2r[8], hi2r[8];
    int k2a = max(0, (k1a >> 1) - 1);
    #pragma unroll
    for (int t = 0; t < 8; ++t) {
        int k = k2a + t;
        float aL = 0.f, aH = 0.f;
        if (k <= 2050) {
            #pragma unroll
            for (int j = 0; j < 6; ++j) {
                int idx = 2 * k - 4 + j - k1a;
                if (idx >= 0 && idx < 8) {
                    aL = fmaf(LO_R[j], lo1r[idx], aL);
                    aH = fmaf(HI_RV[j], lo1r[idx], aH);
                }
            }
        }
        lo2r[t] = aL; hi2r[t] = aH;
    }
    float lo3r[8], hi3r[8];
    int k3a = max(0, (k2a >> 1) - 1);
    #pragma unroll
    for (int t = 0; t < 8; ++t) {
        int k = k3a + t;
        float aL = 0.f, aH = 0.f;
        if (k <= 1027) {
            #pragma unroll
            for (int j = 0; j < 6; ++j) {
                int idx = 2 * k - 4 + j - k2a;
                if (idx >= 0 && idx < 8) {
                    aL = fmaf(LO_R[j], lo2r[idx], aL);
                    aH = fmaf(HI_RV[j], lo2r[idx], aH);
                }
            }
        }
        lo3r[t] = aL; hi3r[t] = aH;
    }
    float g1 = 0.f, g2 = 0.f, g3 = 0.f, w3 = 0.f;
    #pragma unroll
    for (int t = 0; t < 8; ++t) {
        g1 = fmaf(hi1r[t], hi1r[t], g1);
        g2 = fmaf(hi2r[t], hi2r[t], g2);
        g3 = fmaf(hi3r[t], hi3r[t], g3);
        w3 += lo3r[t];
    }
    Tdiag[a] = make_float4(w3, g1, g2, g3);
    float* rp = resp + (size_t)a * 32;
    #pragma unroll
    for (int t = 0; t < 8; ++t) { rp[t] = hi1r[t]; rp[8 + t] = hi2r[t]; rp[16 + t] = hi3r[t]; }
    rp[24] = __int_as_float(k1a);
    rp[25] = __int_as_float(k2a);
    rp[26] = __int_as_float(k3a);
}

// Off-diagonal Gram tables, one thread per (a, d). Band-packed per a (60 floats):
//   [0..19] d=1..5: float4 (G1,G2,G3,0); [20..39] d=6..15: float2 (G2,G3);
//   [40..59] d=16..35: float (G3). Total 1.97 MB -> per-XCD-L2-resident.
__global__ void k_gram(const float* __restrict__ resp, float* __restrict__ GtP) {
    int idx = blockIdx.x * 256 + threadIdx.x;
    if (idx >= NE * 35) return;
    int a = idx / 35;
    int d = idx - a * 35 + 1;  // 1..35
    int b = a + d;
    float v1 = 0.f, v2 = 0.f, v3 = 0.f;
    const float* ra = resp + (size_t)a * 32;
    if (b < NE) {
        const float* rb = resp + (size_t)b * 32;
        {
            int s = __float_as_int(rb[26]) - __float_as_int(ra[26]);
            #pragma unroll
            for (int u = 0; u < 8; ++u) {
                int t = u + s;
                if (t >= 0 && t < 8) v3 = fmaf(rb[16 + u], ra[16 + t], v3);
            }
        }
        if (d <= 15) {
            int s = __float_as_int(rb[25]) - __float_as_int(ra[25]);
            #pragma unroll
            for (int u = 0; u < 8; ++u) {
                int t = u + s;
                if (t >= 0 && t < 8) v2 = fmaf(rb[8 + u], ra[8 + t], v2);
            }
        }
        if (d <= 5) {
            int s = __float_as_int(rb[24]) - __float_as_int(ra[24]);
            #pragma unroll
            for (int u = 0; u < 8; ++u) {
                int t = u + s;
                if (t >= 0 && t < 8) v1 = fmaf(rb[u], ra[t], v1);
            }
        }
    }
    float* g = GtP + (size_t)a * 60;
    if (d <= 5) {
        *(float4*)(g + 4 * (d - 1)) = make_float4(v1, v2, v3, 0.f);
    } else if (d <= 15) {
        *(float2*)(g + 20 + 2 * (d - 6)) = make_float2(v2, v3);
    } else {
        g[40 + (d - 16)] = v3;
    }
}

// Histograms + bucket-count slices (bucket = row >> 4).
__global__ __launch_bounds__(HT) void k_hist3(const int* __restrict__ ui,
                                              const int* __restrict__ ii,
                                              const float* __restrict__ v, int nnz,
                                              int* __restrict__ sliceU,
                                              int* __restrict__ sliceI,
                                              float* __restrict__ sliceS,
                                              int* __restrict__ bsU,
                                              int* __restrict__ bsI) {
    __shared__ int hU[NE];
    __shared__ int hI[NE];
    __shared__ float hS[NE];
    int b = blockIdx.x, tid = threadIdx.x, hb = gridDim.x;
    int4* hU4 = (int4*)hU; int4* hI4 = (int4*)hI; int4* hS4 = (int4*)hS;
    int4 z4 = make_int4(0, 0, 0, 0);
    for (int j = tid; j < NE / 4; j += HT) { hU4[j] = z4; hI4[j] = z4; hS4[j] = z4; }
    __syncthreads();
    int C = (nnz + hb - 1) / hb;
    int beg = b * C, end = min(nnz, beg + C);
    for (int n = beg + tid; n < end; n += HT) {
        atomicAdd(&hU[ui[n]], 1);
        int it = ii[n];
        atomicAdd(&hI[it], 1);
        atomicAdd(&hS[it], v[n]);
    }
    __syncthreads();
    size_t base = (size_t)b * NE;
    int4* sU = (int4*)(sliceU + base); int4* sI = (int4*)(sliceI + base);
    int4* sS = (int4*)(sliceS + base);
    for (int j = tid; j < NE / 4; j += HT) { sU[j] = hU4[j]; sI[j] = hI4[j]; sS[j] = hS4[j]; }
    // bucket counts (sum of 16 consecutive rows)
    for (int b2 = tid; b2 < NBK; b2 += HT) {
        int sUu = 0, sIi = 0;
        int b16 = b2 * 16;
        #pragma unroll
        for (int t = 0; t < 16; ++t) { sUu += hU[b16 + t]; sIi += hI[b16 + t]; }
        bsU[(size_t)b * NBK + b2] = sUu;
        bsI[(size_t)b * NBK + b2] = sIi;
    }
}

__global__ void k_chunksum3(const int* __restrict__ sliceU, const int* __restrict__ sliceI,
                            const float* __restrict__ sliceS, int spc,
                            int* __restrict__ csU, int* __restrict__ csI,
                            float* __restrict__ csS) {
    int i = blockIdx.x * 256 + threadIdx.x;
    int c = blockIdx.y;
    int b0 = c * spc;
    int cu = 0, ci = 0; float sv = 0.f;
    for (int b = b0; b < b0 + spc; ++b) {
        size_t o = (size_t)b * NE + i;
        cu += sliceU[o]; ci += sliceI[o]; sv += sliceS[o];
    }
    size_t oc = (size_t)c * NE + i;
    csU[oc] = cu; csI[oc] = ci; csS[oc] = sv;
}

__global__ void k_final3(const int* __restrict__ csU, const int* __restrict__ csI,
                         const float* __restrict__ csS,
                         int* cntU, int* cntI, float* popraw, float* normAcc) {
    __shared__ float red[4];
    int i = blockIdx.x * 256 + threadIdx.x;
    int cu = 0, ci = 0; float sv = 0.f;
    #pragma unroll
    for (int c = 0; c < NCH; ++c) {
        size_t o = (size_t)c * NE + i;
        cu += csU[o]; ci += csI[o]; sv += csS[o];
    }
    cntU[i] = cu; cntI[i] = ci;
    float p = log1pf((float)ci) * sv;
    popraw[i] = p;
    float s = blockReduceSum(p * p, red);
    if (threadIdx.x == 0) atomicAdd(&normAcc[0], s);
}

__global__ void k_scan2(const int* __restrict__ cntU, const int* __restrict__ cntI,
                        int* ptrU, int* ptrI) {
    __shared__ int sums[256];
    const int* cnt = blockIdx.x ? cntI : cntU;
    int* ptr = blockIdx.x ? ptrI : ptrU;
    int tid = threadIdx.x;
    int base = tid * 32;
    int local[32];
    int s = 0;
    #pragma unroll
    for (int j = 0; j < 32; ++j) { local[j] = cnt[base + j]; s += local[j]; }
    sums[tid] = s;
    __syncthreads();
    for (int off = 1; off < 256; off <<= 1) {
        int t = (tid >= off) ? sums[tid - off] : 0;
        __syncthreads();
        sums[tid] += t;
        __syncthreads();
    }
    int run = (tid > 0) ? sums[tid - 1] : 0;
    #pragma unroll
    for (int j = 0; j < 32; ++j) { ptr[base + j] = run; run += local[j]; }
    if (tid == 255) ptr[NE] = run;
}

// Bucket-cursor machinery: 512 columns per direction, 256 slices in 8 chunks of 32.
__global__ void k_bchunk(const int* __restrict__ bsU, const int* __restrict__ bsI,
                         int* __restrict__ bcsU, int* __restrict__ bcsI) {
    int col = blockIdx.x * 256 + threadIdx.x;
    int c = blockIdx.y;
    const int* bs = blockIdx.z ? bsI : bsU;
    int* bcs = blockIdx.z ? bcsI : bcsU;
    int s = 0;
    int b0 = c * 32;
    for (int b = b0; b < b0 + 32; ++b) s += bs[(size_t)b * NBK + col];
    bcs[(size_t)c * NBK + col] = s;
}

__global__ void k_bscan(int* __restrict__ bcsU, int* __restrict__ bcsI,
                        const int* __restrict__ ptrU, const int* __restrict__ ptrI) {
    int col = blockIdx.x * 256 + threadIdx.x;
    int* bcs = blockIdx.y ? bcsI : bcsU;
    const int* ptr = blockIdx.y ? ptrI : ptrU;
    int run = ptr[col * NROWS];  // bucket base
    #pragma unroll
    for (int c = 0; c < 8; ++c) {
        size_t o = (size_t)c * NBK + col;
        int t = bcs[o]; bcs[o] = run; run += t;
    }
}

__global__ void k_bfine(int* __restrict__ bsU, int* __restrict__ bsI,
                        const int* __restrict__ bcsU, const int* __restrict__ bcsI) {
    int col = blockIdx.x * 256 + threadIdx.x;
    int c = blockIdx.y;
    int* bs = blockIdx.z ? bsI : bsU;
    const int* bcs = blockIdx.z ? bcsI : bcsU;
    int run = bcs[(size_t)c * NBK + col];
    int b0 = c * 32;
    for (int b = b0; b < b0 + 32; ++b) {
        size_t o = (size_t)b * NBK + col;
        int t = bs[o]; bs[o] = run; run += t;
    }
}

// Fused: bucket-granularity scatters (both directions, tagged pairs) + activity
// histogram. 512 cursors/dir in LDS (was 8192); pair runs ~7.6 entries -> ~1
// sector each (write amp ~1.1x vs ~3-4x at per-row granularity).
__global__ __launch_bounds__(HT) void k_scatter2(const int* __restrict__ ui,
                                                 const int* __restrict__ ii,
                                                 const float* __restrict__ v, int nnz,
                                                 const int* __restrict__ bsU,
                                                 const int* __restrict__ bsI,
                                                 const float* __restrict__ popraw,
                                                 const float* __restrict__ normAcc,
                                                 int2* __restrict__ pairsU,
                                                 int2* __restrict__ pairsI,
                                                 float* __restrict__ sliceA) {
    __shared__ int curU[NBK];
    __shared__ int curI[NBK];
    __shared__ float hA[NE];
    int b = blockIdx.x, tid = threadIdx.x, hb = gridDim.x;
    for (int j = tid; j < NBK; j += HT) {
        curU[j] = bsU[(size_t)b * NBK + j];
        curI[j] = bsI[(size_t)b * NBK + j];
    }
    float4* hA4 = (float4*)hA;
    float4 zf = make_float4(0.f, 0.f, 0.f, 0.f);
    for (int j = tid; j < NE / 4; j += HT) hA4[j] = zf;
    __syncthreads();
    float rs0 = 1.f / (sqrtf(normAcc[0]) + 1e-8f);
    int C = (nnz + hb - 1) / hb;
    int beg = b * C, end = min(nnz, beg + C);
    for (int n = beg + tid; n < end; n += HT) {
        int u = ui[n], it = ii[n];
        float val = v[n];
        atomicAdd(&hA[u], val / log1pf(popraw[it] * rs0 + 1e-8f));
        int pU = atomicAdd(&curU[u >> 4], 1);
        pairsU[pU] = make_int2(((u & 15) << 13) | it, __float_as_int(val));
        int pI = atomicAdd(&curI[it >> 4], 1);
        pairsI[pI] = make_int2(((it & 15) << 13) | u, __float_as_int(val));
    }
    __syncthreads();
    float4* sA = (float4*)(sliceA + (size_t)b * NE);
    for (int j = tid; j < NE / 4; j += HT) sA[j] = hA4[j];
}

__global__ void k_actchunk(const float* __restrict__ sliceA, int spc, float* __restrict__ csA) {
    int i = blockIdx.x * 256 + threadIdx.x;
    int c = blockIdx.y;
    int b0 = c * spc;
    float a = 0.f;
    for (int b = b0; b < b0 + spc; ++b) a += sliceA[(size_t)b * NE + i];
    csA[(size_t)c * NE + i] = a;
}

__global__ void k_actfinal(const float* __restrict__ csA, float* act, float* normAcc) {
    __shared__ float red[4];
    int i = blockIdx.x * 256 + threadIdx.x;
    float a = 0.f;
    #pragma unroll
    for (int c = 0; c < NCH; ++c) a += csA[(size_t)c * NE + i];
    act[i] = a;
    float s = blockReduceSum(a * a, red);
    if (threadIdx.x == 0) atomicAdd(&normAcc[1], s);
}

// Per-nnz Gram evaluation; band-packed GtP -> one aligned load per hit.
__device__ __forceinline__ void scan_one(int p, float v, float4 td,
                                         const float* __restrict__ X,
                                         const unsigned int* __restrict__ Mrow,
                                         const float* __restrict__ GtP,
                                         float& s1, float& s2, float& s3, float& ls) {
    float xp = X[p];
    ls = fmaf(v, td.x, ls);
    float vx = v * xp;
    s1 = fmaf(vx, td.y, s1);
    s2 = fmaf(vx, td.z, s2);
    s3 = fmaf(vx, td.w, s3);
    int w = p >> 5, sh = (p & 31) + 1;  // sh in [1,32]
    unsigned long long lo64 = (unsigned long long)Mrow[w] |
                              ((unsigned long long)Mrow[w + 1] << 32);
    unsigned long long win = (lo64 >> sh) |
                             ((unsigned long long)Mrow[w + 2] << (64 - sh));
    win &= (1ull << 35) - 1ull;
    const float* g = GtP + (size_t)p * 60;
    while (win) {
        int d = __ffsll((unsigned long long)win);
        win &= win - 1;
        float c = 2.f * v * X[p + d];
        if (d <= 5) {
            float4 G = *(const float4*)(g + 4 * (d - 1));
            s1 = fmaf(c, G.x, s1);
            s2 = fmaf(c, G.y, s2);
            s3 = fmaf(c, G.z, s3);
        } else if (d <= 15) {
            float2 G = *(const float2*)(g + 20 + 2 * (d - 6));
            s2 = fmaf(c, G.x, s2);
            s3 = fmaf(c, G.y, s3);
        } else {
            s3 = fmaf(c, g[40 + (d - 16)], s3);
        }
    }
}

// Persistent merged rows kernel. Prologue: in-place sort of this block's
// bucket (tagged pairs) into row order (regs -> 16-counter LDS hist ->
// rank-scatter back to global; __threadfence for same-block visibility).
// Body: proven round-17 structure (3 barriers/row, wave-skip reduce),
// row offsets from LDS rowOff instead of global ptr.
__global__ __launch_bounds__(RT) void k_rows(const int* __restrict__ ptrU,
                                             const int* __restrict__ ptrI,
                                             int2* __restrict__ pairsU,
                                             int2* __restrict__ pairsI,
                                             const float* __restrict__ popraw,
                                             const float* __restrict__ actraw,
                                             const float* __restrict__ normAcc,
                                             const float4* __restrict__ Tdiag,
                                             const float* __restrict__ GtP,
                                             float* __restrict__ u_w,
                                             float* __restrict__ i_w) {
    __shared__ __align__(16) float X[NE];        // 32 KB merged row values
    __shared__ unsigned int M[264];              // presence bitmask + pad words
    __shared__ float acc[NROWS][4];              // deferred per-row sums
    __shared__ int rowOff[NROWS + 1];
    __shared__ int rowCur[NROWS];
    int tid = threadIdx.x;
    int bid = blockIdx.x;
    bool isUser = bid >= NBK;
    int bk = isUser ? bid - NBK : bid;
    int r0 = bk * NROWS;
    const int* ptr = isUser ? ptrU : ptrI;
    int2* pairs = isUser ? pairsU : pairsI;
    const float* raw = isUser ? actraw : popraw;
    float* w_out = isUser ? u_w : i_w;
    float rs = 1.f / (sqrtf(normAcc[isUser ? 1 : 0]) + 1e-8f);

    float4* X4 = (float4*)X;
    const float4 z4 = make_float4(0.f, 0.f, 0.f, 0.f);
    for (int q = tid; q < NE / 4; q += RT) X4[q] = z4;
    if (tid < 264) M[tid] = 0u;
    if (tid < NROWS * 4) ((float*)acc)[tid] = 0.f;
    if (tid <= NROWS) rowOff[tid] = 0;
    __syncthreads();

    // ---- prologue: bucket sort ----
    int base = ptr[r0];
    int endB = ptr[r0 + NROWS];
    int cap = base + KMAX * RT;
    if (endB > cap) endB = cap;  // unreachable for this dataset (19 sigma)
    int2 kk[KMAX];
    #pragma unroll
    for (int t = 0; t < KMAX; ++t) {
        int n = base + t * RT + tid;
        kk[t] = (n < endB) ? pairs[n] : make_int2(-1, 0);
        if (kk[t].x >= 0) atomicAdd(&rowOff[1 + (kk[t].x >> 13)], 1);
    }
    __syncthreads();
    if (tid == 0) {
        int run = 0;
        #pragma unroll
        for (int j = 1; j <= NROWS; ++j) { int t = rowOff[j]; rowOff[j] = run + t; run += t; }
    }
    __syncthreads();
    if (tid < NROWS) rowCur[tid] = rowOff[tid];
    __syncthreads();
    #pragma unroll
    for (int t = 0; t < KMAX; ++t) {
        if (kk[t].x >= 0) {
            int tag = kk[t].x >> 13;
            int pos = atomicAdd(&rowCur[tag], 1);
            pairs[base + pos] = make_int2(kk[t].x & 8191, kk[t].y);
        }
    }
    __threadfence();   // flush sorted writes + invalidate L1 before re-reads
    __syncthreads();

    // ---- body ----
    int beg = base, end = base + rowOff[1];
    int2 pr = make_int2(0, 0);
    float4 td = z4;
    if (tid < end - beg) {
        pr = pairs[beg + tid];
        td = Tdiag[pr.x];
    }

    for (int j = 0; j < NROWS; ++j) {
        __syncthreads();  // clears (and init) done; pr/td loaded

        int cnt = end - beg;
        if (tid < cnt) {
            int p = pr.x;
            atomicAdd(&X[p], __int_as_float(pr.y));
            atomicOr(&M[p >> 5], 1u << (p & 31));
        }
        for (int n = beg + RT + tid; n < end; n += RT) {  // overflow (cnt > 512)
            int2 q2 = pairs[n];
            atomicAdd(&X[q2.x], __int_as_float(q2.y));
            atomicOr(&M[q2.x >> 5], 1u << (q2.x & 31));
        }
        __syncthreads();  // scatter done

        // prefetch next row's pairs + Tdiag
        int begN = end, endN = end;
        int2 prN = make_int2(0, 0);
        float4 tdN = z4;
        if (j + 1 < NROWS) {
            endN = base + rowOff[j + 2];
            if (tid < endN - begN) {
                prN = pairs[begN + tid];
                tdN = Tdiag[prN.x];
            }
        }

        // scan row j
        float s1 = 0.f, s2 = 0.f, s3 = 0.f, ls = 0.f;
        if (tid < cnt)
            scan_one(pr.x, __int_as_float(pr.y), td, X, M, GtP, s1, s2, s3, ls);
        for (int n = beg + RT + tid; n < end; n += RT) {
            int2 q2 = pairs[n];
            scan_one(q2.x, __int_as_float(q2.y), Tdiag[q2.x], X, M, GtP,
                     s1, s2, s3, ls);
        }

        // wave-level reduce on active waves only
        int nwav = min(8, (cnt + 63) >> 6);
        if ((tid >> 6) < nwav) {
            #pragma unroll
            for (int off = 32; off > 0; off >>= 1) {
                s1 += __shfl_down(s1, off);
                s2 += __shfl_down(s2, off);
                s3 += __shfl_down(s3, off);
                ls += __shfl_down(ls, off);
            }
            if ((tid & 63) == 0) {
                atomicAdd(&acc[j][0], s1);
                atomicAdd(&acc[j][1], s2);
                atomicAdd(&acc[j][2], s3);
                atomicAdd(&acc[j][3], ls);
            }
        }
        __syncthreads();  // all scan reads done before clears

        if (tid < cnt) { X[pr.x] = 0.f; M[pr.x >> 5] = 0u; }
        for (int n = beg + RT + tid; n < end; n += RT) {
            int2 q2 = pairs[n];
            X[q2.x] = 0.f; M[q2.x >> 5] = 0u;
        }
        beg = begN; end = endN; pr = prN; td = tdN;
    }

    __syncthreads();
    if (tid < NROWS) {
        float t1 = acc[tid][0], t2 = acc[tid][1], t3 = acc[tid][2], tl = acc[tid][3];
        float rawv = raw[r0 + tid];
        float sc = 1.f + rawv * rs;
        float high = (sqrtf(fmaxf(t1, 0.f)) + sqrtf(fmaxf(t2, 0.f)) +
                      sqrtf(fmaxf(t3, 0.f))) * sc;
        float low = tl * (1.f / 1028.f) * sc;
        float a1 = fmaxf(low, 1e-6f);
        float a2 = fmaxf(high, 1e-6f);
        w_out[r0 + tid] = a1 / (a1 + a2);
    }
}

// 4 nnz per thread, float4 loads and stores.
__global__ void k_out(const int* __restrict__ ui, const int* __restrict__ ii,
                      const float* __restrict__ v, int nnz,
                      const float* __restrict__ u_w, const float* __restrict__ i_w,
                      float* __restrict__ out) {
    int ngroups = nnz >> 2;
    int idx = blockIdx.x * blockDim.x + threadIdx.x;
    int stride = gridDim.x * blockDim.x;
    const int4* ui4 = (const int4*)ui;
    const int4* ii4 = (const int4*)ii;
    const float4* v4 = (const float4*)v;
    float4* o0 = (float4*)out;
    float4* o1 = (float4*)(out + (size_t)nnz);
    float4* o2 = (float4*)(out + 2 * (size_t)nnz);
    float4* o3 = (float4*)(out + 3 * (size_t)nnz);
    for (int g = idx; g < ngroups; g += stride) {
        int4 u = ui4[g];
        int4 it = ii4[g];
        float4 val = v4[g];
        float wu0 = u_w[u.x], wu1 = u_w[u.y], wu2 = u_w[u.z], wu3 = u_w[u.w];
        float wi0 = i_w[it.x], wi1 = i_w[it.y], wi2 = i_w[it.z], wi3 = i_w[it.w];
        o0[g] = make_float4(val.x * wu0 * wi0, val.y * wu1 * wi1,
                            val.z * wu2 * wi2, val.w * wu3 * wi3);
        o1[g] = make_float4(val.x * (1.f - wu0) * (1.f - wi0), val.y * (1.f - wu1) * (1.f - wi1),
                            val.z * (1.f - wu2) * (1.f - wi2), val.w * (1.f - wu3) * (1.f - wi3));
        o2[g] = make_float4(val.x * wu0 * (1.f - wi0), val.y * wu1 * (1.f - wi1),
                            val.z * wu2 * (1.f - wi2), val.w * wu3 * (1.f - wi3));
        o3[g] = make_float4(val.x * (1.f - wu0) * wi0, val.y * (1.f - wu1) * wi1,
                            val.z * (1.f - wu2) * wi2, val.w * (1.f - wu3) * wi3);
    }
    int tail = ngroups * 4;
    for (int n = tail + idx; n < nnz; n += stride) {
        float val = v[n];
        float wu = u_w[ui[n]], wi = i_w[ii[n]];
        out[n] = val * wu * wi;
        out[(size_t)nnz + n] = val * (1.f - wu) * (1.f - wi);
        out[2 * (size_t)nnz + n] = val * wu * (1.f - wi);
        out[3 * (size_t)nnz + n] = val * (1.f - wu) * wi;
    }
}

extern "C" void kernel_launch(void* const* d_in, const int* in_sizes, int n_in,
                              void* d_out, int out_size, void* d_ws, size_t ws_size,
                              hipStream_t stream) {
    const int* ui = (const int*)d_in[0];
    const int* ii = (const int*)d_in[1];
    const float* vals = (const float*)d_in[2];
    int nnz = in_sizes[0];
    float* out = (float*)d_out;

    char* ws = (char*)d_ws;
    size_t off = 0;
    auto take = [&](size_t bytes) -> char* {
        char* p = ws + off;
        off = (off + bytes + 255) & ~(size_t)255;
        return p;
    };

    int*   cntU    = (int*)take(NE * 4);
    int*   cntI    = (int*)take(NE * 4);
    float* popraw  = (float*)take(NE * 4);
    float* actraw  = (float*)take(NE * 4);
    int*   ptrU    = (int*)take((NE + 1) * 4);
    int*   ptrI    = (int*)take((NE + 1) * 4);
    float* u_w     = (float*)take(NE * 4);
    float* i_w     = (float*)take(NE * 4);
    float* normAcc = (float*)take(256);
    float4* Tdiag  = (float4*)take((size_t)NE * 16);
    float* GtP     = (float*)take((size_t)NE * 60 * 4);
    float* resp    = (float*)take((size_t)NE * 32 * 4);
    int*   csU     = (int*)take((size_t)NCH * NE * 4);
    int*   csI     = (int*)take((size_t)NCH * NE * 4);
    float* csS     = (float*)take((size_t)NCH * NE * 4);  // reused as csA
    int2*  pairsU  = (int2*)take((size_t)nnz * 8);
    int2*  pairsI  = (int2*)take((size_t)nnz * 8);
    int*   bcsU    = (int*)take((size_t)8 * NBK * 4);
    int*   bcsI    = (int*)take((size_t)8 * NBK * 4);
    size_t fixedEnd = off;

    int hb = 256;
    while (hb > 8 && fixedEnd + 3 * (size_t)hb * NE * 4 +
                     2 * (size_t)hb * NBK * 4 + 4096 > ws_size) hb >>= 1;
    int spc = hb / NCH;
    int*   sliceU = (int*)take((size_t)hb * NE * 4);
    int*   sliceI = (int*)take((size_t)hb * NE * 4);
    float* sliceS = (float*)take((size_t)hb * NE * 4);  // reused as sliceA
    int*   bsU    = (int*)take((size_t)hb * NBK * 4);
    int*   bsI    = (int*)take((size_t)hb * NBK * 4);

    hipMemsetAsync(normAcc, 0, 256, stream);

    int nb = (nnz / 4 + 255) / 256;
    if (nb > 2048) nb = 2048;

    // Gram tables (independent of data)
    k_tables<<<NE / 64, 64, 0, stream>>>(resp, Tdiag);
    k_gram<<<(NE * 35 + 255) / 256, 256, 0, stream>>>(resp, GtP);

    // popularity + counts + bucket counts
    k_hist3<<<hb, HT, 0, stream>>>(ui, ii, vals, nnz, sliceU, sliceI, sliceS, bsU, bsI);
    k_chunksum3<<<dim3(32, NCH), 256, 0, stream>>>(sliceU, sliceI, sliceS, spc, csU, csI, csS);
    k_final3<<<32, 256, 0, stream>>>(csU, csI, csS, cntU, cntI, popraw, normAcc);

    // row ptr (for bucket bases + final3 deps) and bucket cursors
    k_scan2<<<2, 256, 0, stream>>>(cntU, cntI, ptrU, ptrI);
    k_bchunk<<<dim3(2, 8, 2), 256, 0, stream>>>(bsU, bsI, bcsU, bcsI);
    k_bscan<<<dim3(2, 2), 256, 0, stream>>>(bcsU, bcsI, ptrU, ptrI);
    k_bfine<<<dim3(2, 8, 2), 256, 0, stream>>>(bsU, bsI, bcsU, bcsI);

    // fused bucket scatters + activity histogram partials
    k_scatter2<<<hb, HT, 0, stream>>>(ui, ii, vals, nnz, bsU, bsI,
                                      popraw, normAcc, pairsU, pairsI, sliceS);

    // finish activity norm
    k_actchunk<<<dim3(32, NCH), 256, 0, stream>>>(sliceS, spc, csS);
    k_actfinal<<<32, 256, 0, stream>>>(csS, actraw, normAcc);

    // persistent merged item + user rows (bucket sort prologue + Gram body)
    k_rows<<<2 * NBK, RT, 0, stream>>>(ptrU, ptrI, pairsU, pairsI,
                                       popraw, actraw, normAcc, Tdiag, GtP, u_w, i_w);

    k_out<<<nb, 256, 0, stream>>>(ui, ii, vals, nnz, u_w, i_w, out);
}

// Round 19
// 237.813 us; speedup vs baseline: 2.1630x; 2.1630x over previous
//
#include <hip/hip_runtime.h>
#include <math.h>

#define NE 8192   // num_users == num_items
#define HT 1024   // histogram/scatter block threads
#define NCH 8     // slice chunks for two-level colscan/reduce
#define RT 512    // k_rows threads (8 waves)
#define NROWS 16  // rows per k_rows block (grid 1024 = 4 blocks/CU exactly)

// db3 analysis filters, reversed (cross-correlation of reversed filter == convolution)
__device__ __constant__ float LO_R[6] = {
    0.3326705529509569f, 0.8068915093133388f, 0.4598775021193313f,
    -0.13501102001039084f, -0.08544127388224149f, 0.035226291882100656f};
__device__ __constant__ float HI_RV[6] = {
    0.035226291882100656f, 0.08544127388224149f, -0.13501102001039084f,
    -0.4598775021193313f, 0.8068915093133388f, -0.3326705529509569f};

// 256-thread block reduce; valid on thread 0.
__device__ __forceinline__ float blockReduceSum(float v, float* red) {
    #pragma unroll
    for (int off = 32; off > 0; off >>= 1) v += __shfl_down(v, off);
    int lane = threadIdx.x & 63, wid = threadIdx.x >> 6;
    if (lane == 0) red[wid] = v;
    __syncthreads();
    float r = 0.f;
    if (threadIdx.x == 0) {
        int nw = blockDim.x >> 6;
        for (int i = 0; i < nw; ++i) r += red[i];
    }
    return r;
}

// ---------- setup: per-position impulse responses of the 3-level clipped DWT ----
__global__ void k_tables(float* __restrict__ resp, float4* __restrict__ Tdiag) {
    int a = blockIdx.x * blockDim.x + threadIdx.x;
    if (a >= NE) return;
    float lo1r[8], hi1r[8];
    int k1a = max(0, (a >> 1) - 3);
    #pragma unroll
    for (int t = 0; t < 8; ++t) {
        int k = k1a + t;
        int j = a - 2 * k + 4;
        bool ok = (j >= 0 && j <= 5 && k <= 4097);
        lo1r[t] = ok ? LO_R[j] : 0.f;
        hi1r[t] = ok ? HI_RV[j] : 0.f;
    }
    float lo2r[8], hi2r[8];
    int k2a = max(0, (k1a >> 1) - 1);
    #pragma unroll
    for (int t = 0; t < 8; ++t) {
        int k = k2a + t;
        float aL = 0.f, aH = 0.f;
        if (k <= 2050) {
            #pragma unroll
            for (int j = 0; j < 6; ++j) {
                int idx = 2 * k - 4 + j - k1a;
                if (idx >= 0 && idx < 8) {
                    aL = fmaf(LO_R[j], lo1r[idx], aL);
                    aH = fmaf(HI_RV[j], lo1r[idx], aH);
                }
            }
        }
        lo2r[t] = aL; hi2r[t] = aH;
    }
    float lo3r[8], hi3r[8];
    int k3a = max(0, (k2a >> 1) - 1);
    #pragma unroll
    for (int t = 0; t < 8; ++t) {
        int k = k3a + t;
        float aL = 0.f, aH = 0.f;
        if (k <= 1027) {
            #pragma unroll
            for (int j = 0; j < 6; ++j) {
                int idx = 2 * k - 4 + j - k2a;
                if (idx >= 0 && idx < 8) {
                    aL = fmaf(LO_R[j], lo2r[idx], aL);
                    aH = fmaf(HI_RV[j], lo2r[idx], aH);
                }
            }
        }
        lo3r[t] = aL; hi3r[t] = aH;
    }
    float g1 = 0.f, g2 = 0.f, g3 = 0.f, w3 = 0.f;
    #pragma unroll
    for (int t = 0; t < 8; ++t) {
        g1 = fmaf(hi1r[t], hi1r[t], g1);
        g2 = fmaf(hi2r[t], hi2r[t], g2);
        g3 = fmaf(hi3r[t], hi3r[t], g3);
        w3 += lo3r[t];
    }
    Tdiag[a] = make_float4(w3, g1, g2, g3);
    float* rp = resp + (size_t)a * 32;
    #pragma unroll
    for (int t = 0; t < 8; ++t) { rp[t] = hi1r[t]; rp[8 + t] = hi2r[t]; rp[16 + t] = hi3r[t]; }
    rp[24] = __int_as_float(k1a);
    rp[25] = __int_as_float(k2a);
    rp[26] = __int_as_float(k3a);
}

// Off-diagonal Gram tables, one thread per (a, d). BAND-PACKED layout per a
// (60 floats = 240 B; total 1.97 MB -> per-XCD-L2-resident):
//   [0..19]  d=1..5  : float4 (G1,G2,G3,0)
//   [20..39] d=6..15 : float2 (G2,G3)
//   [40..59] d=16..35: float  (G3)
__global__ void k_gram(const float* __restrict__ resp, float* __restrict__ GtP) {
    int idx = blockIdx.x * 256 + threadIdx.x;
    if (idx >= NE * 35) return;
    int a = idx / 35;
    int d = idx - a * 35 + 1;  // 1..35
    int b = a + d;
    float v1 = 0.f, v2 = 0.f, v3 = 0.f;
    const float* ra = resp + (size_t)a * 32;
    if (b < NE) {
        const float* rb = resp + (size_t)b * 32;
        {   // level 3 always
            int s = __float_as_int(rb[26]) - __float_as_int(ra[26]);
            #pragma unroll
            for (int u = 0; u < 8; ++u) {
                int t = u + s;
                if (t >= 0 && t < 8) v3 = fmaf(rb[16 + u], ra[16 + t], v3);
            }
        }
        if (d <= 15) {
            int s = __float_as_int(rb[25]) - __float_as_int(ra[25]);
            #pragma unroll
            for (int u = 0; u < 8; ++u) {
                int t = u + s;
                if (t >= 0 && t < 8) v2 = fmaf(rb[8 + u], ra[8 + t], v2);
            }
        }
        if (d <= 5) {
            int s = __float_as_int(rb[24]) - __float_as_int(ra[24]);
            #pragma unroll
            for (int u = 0; u < 8; ++u) {
                int t = u + s;
                if (t >= 0 && t < 8) v1 = fmaf(rb[u], ra[t], v1);
            }
        }
    }
    float* g = GtP + (size_t)a * 60;
    if (d <= 5) {
        *(float4*)(g + 4 * (d - 1)) = make_float4(v1, v2, v3, 0.f);
    } else if (d <= 15) {
        *(float2*)(g + 20 + 2 * (d - 6)) = make_float2(v2, v3);
    } else {
        g[40 + (d - 16)] = v3;
    }
}

__global__ __launch_bounds__(HT) void k_hist3(const int* __restrict__ ui,
                                              const int* __restrict__ ii,
                                              const float* __restrict__ v, int nnz,
                                              int* __restrict__ sliceU,
                                              int* __restrict__ sliceI,
                                              float* __restrict__ sliceS) {
    __shared__ int hU[NE];
    __shared__ int hI[NE];
    __shared__ float hS[NE];
    int b = blockIdx.x, tid = threadIdx.x, hb = gridDim.x;
    int4* hU4 = (int4*)hU; int4* hI4 = (int4*)hI; int4* hS4 = (int4*)hS;
    int4 z4 = make_int4(0, 0, 0, 0);
    for (int j = tid; j < NE / 4; j += HT) { hU4[j] = z4; hI4[j] = z4; hS4[j] = z4; }
    __syncthreads();
    int C = (nnz + hb - 1) / hb;
    int beg = b * C, end = min(nnz, beg + C);
    for (int n = beg + tid; n < end; n += HT) {
        atomicAdd(&hU[ui[n]], 1);
        int it = ii[n];
        atomicAdd(&hI[it], 1);
        atomicAdd(&hS[it], v[n]);
    }
    __syncthreads();
    size_t base = (size_t)b * NE;
    int4* sU = (int4*)(sliceU + base); int4* sI = (int4*)(sliceI + base);
    int4* sS = (int4*)(sliceS + base);
    for (int j = tid; j < NE / 4; j += HT) { sU[j] = hU4[j]; sI[j] = hI4[j]; sS[j] = hS4[j]; }
}

__global__ void k_chunksum3(const int* __restrict__ sliceU, const int* __restrict__ sliceI,
                            const float* __restrict__ sliceS, int spc,
                            int* __restrict__ csU, int* __restrict__ csI,
                            float* __restrict__ csS) {
    int i = blockIdx.x * 256 + threadIdx.x;
    int c = blockIdx.y;
    int b0 = c * spc;
    int cu = 0, ci = 0; float sv = 0.f;
    for (int b = b0; b < b0 + spc; ++b) {
        size_t o = (size_t)b * NE + i;
        cu += sliceU[o]; ci += sliceI[o]; sv += sliceS[o];
    }
    size_t oc = (size_t)c * NE + i;
    csU[oc] = cu; csI[oc] = ci; csS[oc] = sv;
}

__global__ void k_final3(const int* __restrict__ csU, const int* __restrict__ csI,
                         const float* __restrict__ csS,
                         int* cntU, int* cntI, float* popraw, float* normAcc) {
    __shared__ float red[4];
    int i = blockIdx.x * 256 + threadIdx.x;
    int cu = 0, ci = 0; float sv = 0.f;
    #pragma unroll
    for (int c = 0; c < NCH; ++c) {
        size_t o = (size_t)c * NE + i;
        cu += csU[o]; ci += csI[o]; sv += csS[o];
    }
    cntU[i] = cu; cntI[i] = ci;
    float p = log1pf((float)ci) * sv;
    popraw[i] = p;
    float s = blockReduceSum(p * p, red);
    if (threadIdx.x == 0) atomicAdd(&normAcc[0], s);
}

__global__ void k_scan2(const int* __restrict__ cntU, const int* __restrict__ cntI,
                        int* ptrU, int* ptrI) {
    __shared__ int sums[256];
    const int* cnt = blockIdx.x ? cntI : cntU;
    int* ptr = blockIdx.x ? ptrI : ptrU;
    int tid = threadIdx.x;
    int base = tid * 32;
    int local[32];
    int s = 0;
    #pragma unroll
    for (int j = 0; j < 32; ++j) { local[j] = cnt[base + j]; s += local[j]; }
    sums[tid] = s;
    __syncthreads();
    for (int off = 1; off < 256; off <<= 1) {
        int t = (tid >= off) ? sums[tid - off] : 0;
        __syncthreads();
        sums[tid] += t;
        __syncthreads();
    }
    int run = (tid > 0) ? sums[tid - 1] : 0;
    #pragma unroll
    for (int j = 0; j < 32; ++j) { ptr[base + j] = run; run += local[j]; }
    if (tid == 255) ptr[NE] = run;
}

__global__ void k_colscanB(int* csU, int* csI,
                           const int* __restrict__ ptrU, const int* __restrict__ ptrI) {
    int i = blockIdx.x * 256 + threadIdx.x;
    int* cs = blockIdx.y ? csI : csU;
    const int* ptr = blockIdx.y ? ptrI : ptrU;
    int run = ptr[i];
    #pragma unroll
    for (int c = 0; c < NCH; ++c) {
        size_t o = (size_t)c * NE + i;
        int t = cs[o]; cs[o] = run; run += t;
    }
}

// Within-chunk scan of slices (in place) seeded with chunk offsets.
__global__ void k_colscanC(int* sliceU, int* sliceI,
                           const int* __restrict__ csU, const int* __restrict__ csI, int spc) {
    int i = blockIdx.x * 256 + threadIdx.x;
    int c = blockIdx.y;
    int* slice = blockIdx.z ? sliceI : sliceU;
    const int* cs = blockIdx.z ? csI : csU;
    int run = cs[(size_t)c * NE + i];
    int b0 = c * spc;
    for (int b = b0; b < b0 + spc; ++b) {
        size_t o = (size_t)b * NE + i;
        int t = slice[o]; slice[o] = run; run += t;
    }
}

// Fused: both counting-sort scatters + user-activity histogram (one nnz pass).
__global__ __launch_bounds__(HT) void k_scatter2(const int* __restrict__ ui,
                                                 const int* __restrict__ ii,
                                                 const float* __restrict__ v, int nnz,
                                                 const int* __restrict__ sliceU,
                                                 const int* __restrict__ sliceI,
                                                 const float* __restrict__ popraw,
                                                 const float* __restrict__ normAcc,
                                                 int2* __restrict__ pairsU,
                                                 int2* __restrict__ pairsI,
                                                 float* __restrict__ sliceA) {
    __shared__ int curU[NE];
    __shared__ int curI[NE];
    __shared__ float hA[NE];
    int b = blockIdx.x, tid = threadIdx.x, hb = gridDim.x;
    const int4* sU = (const int4*)(sliceU + (size_t)b * NE);
    const int4* sI = (const int4*)(sliceI + (size_t)b * NE);
    int4* cU4 = (int4*)curU; int4* cI4 = (int4*)curI;
    float4* hA4 = (float4*)hA;
    float4 zf = make_float4(0.f, 0.f, 0.f, 0.f);
    for (int j = tid; j < NE / 4; j += HT) { cU4[j] = sU[j]; cI4[j] = sI[j]; hA4[j] = zf; }
    __syncthreads();
    float rs0 = 1.f / (sqrtf(normAcc[0]) + 1e-8f);
    int C = (nnz + hb - 1) / hb;
    int beg = b * C, end = min(nnz, beg + C);
    for (int n = beg + tid; n < end; n += HT) {
        int u = ui[n], it = ii[n];
        float val = v[n];
        atomicAdd(&hA[u], val / log1pf(popraw[it] * rs0 + 1e-8f));
        int pU = atomicAdd(&curU[u], 1);
        pairsU[pU] = make_int2(it, __float_as_int(val));
        int pI = atomicAdd(&curI[it], 1);
        pairsI[pI] = make_int2(u, __float_as_int(val));
    }
    __syncthreads();
    float4* sA = (float4*)(sliceA + (size_t)b * NE);
    for (int j = tid; j < NE / 4; j += HT) sA[j] = hA4[j];
}

__global__ void k_actchunk(const float* __restrict__ sliceA, int spc, float* __restrict__ csA) {
    int i = blockIdx.x * 256 + threadIdx.x;
    int c = blockIdx.y;
    int b0 = c * spc;
    float a = 0.f;
    for (int b = b0; b < b0 + spc; ++b) a += sliceA[(size_t)b * NE + i];
    csA[(size_t)c * NE + i] = a;
}

__global__ void k_actfinal(const float* __restrict__ csA, float* act, float* normAcc) {
    __shared__ float red[4];
    int i = blockIdx.x * 256 + threadIdx.x;
    float a = 0.f;
    #pragma unroll
    for (int c = 0; c < NCH; ++c) a += csA[(size_t)c * NE + i];
    act[i] = a;
    float s = blockReduceSum(a * a, red);
    if (threadIdx.x == 0) atomicAdd(&normAcc[1], s);
}

// Per-nnz Gram evaluation; band-packed GtP -> one aligned load per hit.
__device__ __forceinline__ void scan_one(int p, float v, float4 td,
                                         const float* __restrict__ X,
                                         const unsigned int* __restrict__ Mrow,
                                         const float* __restrict__ GtP,
                                         float& s1, float& s2, float& s3, float& ls) {
    float xp = X[p];
    ls = fmaf(v, td.x, ls);
    float vx = v * xp;
    s1 = fmaf(vx, td.y, s1);
    s2 = fmaf(vx, td.z, s2);
    s3 = fmaf(vx, td.w, s3);
    int w = p >> 5, sh = (p & 31) + 1;  // sh in [1,32]
    unsigned long long lo64 = (unsigned long long)Mrow[w] |
                              ((unsigned long long)Mrow[w + 1] << 32);
    unsigned long long win = (lo64 >> sh) |
                             ((unsigned long long)Mrow[w + 2] << (64 - sh));
    win &= (1ull << 35) - 1ull;  // bit (d-1) <-> neighbor at p+d
    const float* g = GtP + (size_t)p * 60;
    while (win) {
        int d = __ffsll((unsigned long long)win);  // 1-based
        win &= win - 1;
        float c = 2.f * v * X[p + d];
        if (d <= 5) {
            float4 G = *(const float4*)(g + 4 * (d - 1));
            s1 = fmaf(c, G.x, s1);
            s2 = fmaf(c, G.y, s2);
            s3 = fmaf(c, G.z, s3);
        } else if (d <= 15) {
            float2 G = *(const float2*)(g + 20 + 2 * (d - 6));
            s2 = fmaf(c, G.x, s2);
            s3 = fmaf(c, G.y, s3);
        } else {
            s3 = fmaf(c, g[40 + (d - 16)], s3);
        }
    }
}

// Persistent merged rows kernel (Gram, 3-barrier structure, band-packed GtP,
// wave-skip reduce).
__global__ __launch_bounds__(RT) void k_rows(const int* __restrict__ ptrU,
                                             const int* __restrict__ ptrI,
                                             const int2* __restrict__ pairsU,
                                             const int2* __restrict__ pairsI,
                                             const float* __restrict__ popraw,
                                             const float* __restrict__ actraw,
                                             const float* __restrict__ normAcc,
                                             const float4* __restrict__ Tdiag,
                                             const float* __restrict__ GtP,
                                             float* __restrict__ u_w,
                                             float* __restrict__ i_w) {
    __shared__ __align__(16) float X[NE];        // 32 KB merged row values
    __shared__ unsigned int M[264];              // presence bitmask + pad words
    __shared__ float acc[NROWS][4];              // deferred per-row sums
    int tid = threadIdx.x;
    int bid = blockIdx.x;
    bool isUser = bid >= 512;
    int r0 = (isUser ? bid - 512 : bid) * NROWS;
    const int* ptr = isUser ? ptrU : ptrI;
    const int2* pairs = isUser ? pairsU : pairsI;
    const float* raw = isUser ? actraw : popraw;
    float* w_out = isUser ? u_w : i_w;
    float rs = 1.f / (sqrtf(normAcc[isUser ? 1 : 0]) + 1e-8f);

    float4* X4 = (float4*)X;
    const float4 z4 = make_float4(0.f, 0.f, 0.f, 0.f);
    for (int q = tid; q < NE / 4; q += RT) X4[q] = z4;
    if (tid < 264) M[tid] = 0u;
    if (tid < NROWS * 4) ((float*)acc)[tid] = 0.f;

    int beg = ptr[r0], end = ptr[r0 + 1];
    int2 pr = make_int2(0, 0);
    float4 td = z4;
    if (tid < end - beg) {
        pr = pairs[beg + tid];
        td = Tdiag[pr.x];
    }

    for (int j = 0; j < NROWS; ++j) {
        int rl = r0 + j;
        __syncthreads();  // clears (and init) done; pr/td loaded

        int cnt = end - beg;
        if (tid < cnt) {
            int p = pr.x;
            atomicAdd(&X[p], __int_as_float(pr.y));
            atomicOr(&M[p >> 5], 1u << (p & 31));
        }
        for (int n = beg + RT + tid; n < end; n += RT) {  // overflow (cnt > 512)
            int2 q2 = pairs[n];
            atomicAdd(&X[q2.x], __int_as_float(q2.y));
            atomicOr(&M[q2.x >> 5], 1u << (q2.x & 31));
        }
        __syncthreads();  // scatter done

        // prefetch next row's pairs + Tdiag (consumed next iteration)
        int begN = end, endN = end;
        int2 prN = make_int2(0, 0);
        float4 tdN = z4;
        if (j + 1 < NROWS) {
            endN = ptr[rl + 2];
            if (tid < endN - begN) {
                prN = pairs[begN + tid];
                tdN = Tdiag[prN.x];
            }
        }

        // scan row j
        float s1 = 0.f, s2 = 0.f, s3 = 0.f, ls = 0.f;
        if (tid < cnt)
            scan_one(pr.x, __int_as_float(pr.y), td, X, M, GtP, s1, s2, s3, ls);
        for (int n = beg + RT + tid; n < end; n += RT) {
            int2 q2 = pairs[n];
            scan_one(q2.x, __int_as_float(q2.y), Tdiag[q2.x], X, M, GtP,
                     s1, s2, s3, ls);
        }

        // wave-level reduce on active waves only (block-uniform bound)
        int nwav = min(8, (cnt + 63) >> 6);
        if ((tid >> 6) < nwav) {
            #pragma unroll
            for (int off = 32; off > 0; off >>= 1) {
                s1 += __shfl_down(s1, off);
                s2 += __shfl_down(s2, off);
                s3 += __shfl_down(s3, off);
                ls += __shfl_down(ls, off);
            }
            if ((tid & 63) == 0) {
                atomicAdd(&acc[j][0], s1);
                atomicAdd(&acc[j][1], s2);
                atomicAdd(&acc[j][2], s3);
                atomicAdd(&acc[j][3], ls);
            }
        }
        __syncthreads();  // all scan reads done before clears

        // plain-store clear of row j
        if (tid < cnt) { X[pr.x] = 0.f; M[pr.x >> 5] = 0u; }
        for (int n = beg + RT + tid; n < end; n += RT) {
            int2 q2 = pairs[n];
            X[q2.x] = 0.f; M[q2.x >> 5] = 0u;
        }
        beg = begN; end = endN; pr = prN; td = tdN;
    }

    __syncthreads();  // acc atomics + final clears done
    if (tid < NROWS) {
        float t1 = acc[tid][0], t2 = acc[tid][1], t3 = acc[tid][2], tl = acc[tid][3];
        float rawv = raw[r0 + tid];
        float sc = 1.f + rawv * rs;
        float high = (sqrtf(fmaxf(t1, 0.f)) + sqrtf(fmaxf(t2, 0.f)) +
                      sqrtf(fmaxf(t3, 0.f))) * sc;
        float low = tl * (1.f / 1028.f) * sc;
        float a1 = fmaxf(low, 1e-6f);
        float a2 = fmaxf(high, 1e-6f);
        w_out[r0 + tid] = a1 / (a1 + a2);
    }
}

// 4 nnz per thread, float4 loads and stores.
__global__ void k_out(const int* __restrict__ ui, const int* __restrict__ ii,
                      const float* __restrict__ v, int nnz,
                      const float* __restrict__ u_w, const float* __restrict__ i_w,
                      float* __restrict__ out) {
    int ngroups = nnz >> 2;
    int idx = blockIdx.x * blockDim.x + threadIdx.x;
    int stride = gridDim.x * blockDim.x;
    const int4* ui4 = (const int4*)ui;
    const int4* ii4 = (const int4*)ii;
    const float4* v4 = (const float4*)v;
    float4* o0 = (float4*)out;
    float4* o1 = (float4*)(out + (size_t)nnz);
    float4* o2 = (float4*)(out + 2 * (size_t)nnz);
    float4* o3 = (float4*)(out + 3 * (size_t)nnz);
    for (int g = idx; g < ngroups; g += stride) {
        int4 u = ui4[g];
        int4 it = ii4[g];
        float4 val = v4[g];
        float wu0 = u_w[u.x], wu1 = u_w[u.y], wu2 = u_w[u.z], wu3 = u_w[u.w];
        float wi0 = i_w[it.x], wi1 = i_w[it.y], wi2 = i_w[it.z], wi3 = i_w[it.w];
        o0[g] = make_float4(val.x * wu0 * wi0, val.y * wu1 * wi1,
                            val.z * wu2 * wi2, val.w * wu3 * wi3);
        o1[g] = make_float4(val.x * (1.f - wu0) * (1.f - wi0), val.y * (1.f - wu1) * (1.f - wi1),
                            val.z * (1.f - wu2) * (1.f - wi2), val.w * (1.f - wu3) * (1.f - wi3));
        o2[g] = make_float4(val.x * wu0 * (1.f - wi0), val.y * wu1 * (1.f - wi1),
                            val.z * wu2 * (1.f - wi2), val.w * wu3 * (1.f - wi3));
        o3[g] = make_float4(val.x * (1.f - wu0) * wi0, val.y * (1.f - wu1) * wi1,
                            val.z * (1.f - wu2) * wi2, val.w * (1.f - wu3) * wi3);
    }
    int tail = ngroups * 4;
    for (int n = tail + idx; n < nnz; n += stride) {
        float val = v[n];
        float wu = u_w[ui[n]], wi = i_w[ii[n]];
        out[n] = val * wu * wi;
        out[(size_t)nnz + n] = val * (1.f - wu) * (1.f - wi);
        out[2 * (size_t)nnz + n] = val * wu * (1.f - wi);
        out[3 * (size_t)nnz + n] = val * (1.f - wu) * wi;
    }
}

extern "C" void kernel_launch(void* const* d_in, const int* in_sizes, int n_in,
                              void* d_out, int out_size, void* d_ws, size_t ws_size,
                              hipStream_t stream) {
    const int* ui = (const int*)d_in[0];
    const int* ii = (const int*)d_in[1];
    const float* vals = (const float*)d_in[2];
    int nnz = in_sizes[0];
    float* out = (float*)d_out;

    char* ws = (char*)d_ws;
    size_t off = 0;
    auto take = [&](size_t bytes) -> char* {
        char* p = ws + off;
        off = (off + bytes + 255) & ~(size_t)255;
        return p;
    };

    int*   cntU    = (int*)take(NE * 4);
    int*   cntI    = (int*)take(NE * 4);
    float* popraw  = (float*)take(NE * 4);
    float* actraw  = (float*)take(NE * 4);
    int*   ptrU    = (int*)take((NE + 1) * 4);
    int*   ptrI    = (int*)take((NE + 1) * 4);
    float* u_w     = (float*)take(NE * 4);
    float* i_w     = (float*)take(NE * 4);
    float* normAcc = (float*)take(256);
    float4* Tdiag  = (float4*)take((size_t)NE * 16);
    float* GtP     = (float*)take((size_t)NE * 60 * 4);
    float* resp    = (float*)take((size_t)NE * 32 * 4);
    int*   csU     = (int*)take((size_t)NCH * NE * 4);
    int*   csI     = (int*)take((size_t)NCH * NE * 4);
    float* csS     = (float*)take((size_t)NCH * NE * 4);  // reused as csA
    int2*  pairsU  = (int2*)take((size_t)nnz * 8);
    int2*  pairsI  = (int2*)take((size_t)nnz * 8);
    size_t fixedEnd = off;

    int hb = 256;
    while (hb > 8 && fixedEnd + 3 * (size_t)hb * NE * 4 + 4096 > ws_size) hb >>= 1;
    int spc = hb / NCH;
    int*   sliceU = (int*)take((size_t)hb * NE * 4);
    int*   sliceI = (int*)take((size_t)hb * NE * 4);
    float* sliceS = (float*)take((size_t)hb * NE * 4);  // reused as sliceA

    hipMemsetAsync(normAcc, 0, 256, stream);

    int nb = (nnz / 4 + 255) / 256;
    if (nb > 2048) nb = 2048;

    // Gram tables (independent of data) — fully parallel setup
    k_tables<<<NE / 64, 64, 0, stream>>>(resp, Tdiag);
    k_gram<<<(NE * 35 + 255) / 256, 256, 0, stream>>>(resp, GtP);

    // popularity + counts
    k_hist3<<<hb, HT, 0, stream>>>(ui, ii, vals, nnz, sliceU, sliceI, sliceS);
    k_chunksum3<<<dim3(32, NCH), 256, 0, stream>>>(sliceU, sliceI, sliceS, spc, csU, csI, csS);
    k_final3<<<32, 256, 0, stream>>>(csU, csI, csS, cntU, cntI, popraw, normAcc);

    // counting-sort offsets for both tables
    k_scan2<<<2, 256, 0, stream>>>(cntU, cntI, ptrU, ptrI);
    k_colscanB<<<dim3(32, 2), 256, 0, stream>>>(csU, csI, ptrU, ptrI);
    k_colscanC<<<dim3(32, NCH, 2), 256, 0, stream>>>(sliceU, sliceI, csU, csI, spc);

    // one fused pass: both scatters + activity histogram partials
    k_scatter2<<<hb, HT, 0, stream>>>(ui, ii, vals, nnz, sliceU, sliceI,
                                      popraw, normAcc, pairsU, pairsI, sliceS);

    // finish activity norm before the merged rows kernel
    k_actchunk<<<dim3(32, NCH), 256, 0, stream>>>(sliceS, spc, csS);
    k_actfinal<<<32, 256, 0, stream>>>(csS, actraw, normAcc);

    // persistent merged item + user rows
    k_rows<<<1024, RT, 0, stream>>>(ptrU, ptrI, pairsU, pairsI,
                                    popraw, actraw, normAcc, Tdiag, GtP, u_w, i_w);

    k_out<<<nb, 256, 0, stream>>>(ui, ii, vals, nnz, u_w, i_w, out);
}